// Round 2
// baseline (456.423 us; speedup 1.0000x reference)
//
#include <hip/hip_runtime.h>
#include <hip/hip_bf16.h>

#define DIM 128
#define CAP 64       // padded CSR row capacity; in-deg ~Poisson(16), P(>=64) astronomically small
#define NBMAX 64     // max buckets (node-space / 2048)
#define BCAP 36864   // per-bucket edge capacity; mean ~32.7k, +22 sigma margin
#define CSPLIT 8     // sub-blocks per bucket for CSR/hist build (straggler fix, R13)

typedef __attribute__((ext_vector_type(8))) short bf16x8;
typedef __attribute__((ext_vector_type(4))) float f32x4;
typedef __bf16 bf16x2 __attribute__((ext_vector_type(2)));
union U16 { uint4 u; bf16x8 b; };
union UB { unsigned u; bf16x2 h; };

// ---- bf16 pack/unpack helpers (manual, RNE) ----
__device__ __forceinline__ unsigned short f2bf(float f) {
    unsigned u = __float_as_uint(f);
    unsigned r = (u + 0x7fffu + ((u >> 16) & 1u)) >> 16;
    return (unsigned short)r;
}
__device__ __forceinline__ unsigned pack2bf(float a, float b) {
    return (unsigned)f2bf(a) | ((unsigned)f2bf(b) << 16);
}
__device__ __forceinline__ float2 unpack2bf(unsigned v) {
    float2 r;
    r.x = __uint_as_float(v << 16);
    r.y = __uint_as_float(v & 0xffff0000u);
    return r;
}
__device__ __forceinline__ void accum8s(float* acc, uint4 v, float s) {
    float2 f0 = unpack2bf(v.x), f1 = unpack2bf(v.y);
    float2 f2 = unpack2bf(v.z), f3 = unpack2bf(v.w);
    acc[0] += s * f0.x; acc[1] += s * f0.y; acc[2] += s * f1.x; acc[3] += s * f1.y;
    acc[4] += s * f2.x; acc[5] += s * f2.y; acc[6] += s * f3.x; acc[7] += s * f3.y;
}
// R14: native-__bf16 extraction + fmaf -> eligible for gfx950 v_fma_mix_f32_bf16
// (1 instr per element); worst case compiles to shift+fma (same as accum8s).
__device__ __forceinline__ void accum8m(float* acc, uint4 v, float s) {
    UB w0, w1, w2, w3;
    w0.u = v.x; w1.u = v.y; w2.u = v.z; w3.u = v.w;
    acc[0] = fmaf((float)w0.h[0], s, acc[0]);
    acc[1] = fmaf((float)w0.h[1], s, acc[1]);
    acc[2] = fmaf((float)w1.h[0], s, acc[2]);
    acc[3] = fmaf((float)w1.h[1], s, acc[3]);
    acc[4] = fmaf((float)w2.h[0], s, acc[4]);
    acc[5] = fmaf((float)w2.h[1], s, acc[5]);
    acc[6] = fmaf((float)w3.h[0], s, acc[6]);
    acc[7] = fmaf((float)w3.h[1], s, acc[7]);
}

// ================= k_bin: bucket edges (R12-verified) + W1/W2/W3 bf16-T prepack tail ============
__global__ __launch_bounds__(256) void k_bin(const int* __restrict__ src,
                                             const int* __restrict__ dst, int E,
                                             unsigned* __restrict__ binD,
                                             unsigned short* __restrict__ binS,
                                             int* __restrict__ cntD,
                                             int* __restrict__ cntS, int NB, int binGrid,
                                             const float* __restrict__ W1,
                                             const float* __restrict__ W2,
                                             const float* __restrict__ W3,
                                             unsigned* __restrict__ wT1g,
                                             unsigned* __restrict__ wT2g,
                                             unsigned* __restrict__ wT3g) {
    __shared__ int hD[NBMAX], hS[NBMAX], bD[NBMAX], bS[NBMAX];
    int t = threadIdx.x;
    if ((int)blockIdx.x >= binGrid) {
        // ---------- W^T bf16 prepack: wTg[n*64+kp] = pack(W[2kp][n], W[2kp+1][n]) ----------
        int w = blockIdx.x - binGrid;
        const float* Wsrc = (w == 0) ? W1 : (w == 1) ? W2 : W3;
        unsigned* wTg = (w == 0) ? wT1g : (w == 1) ? wT2g : wT3g;
        int n = t >> 1;
        int kp0 = (t & 1) * 32;
#pragma unroll
        for (int i = 0; i < 32; i++) {
            int kp = kp0 + i;
            wTg[n * 64 + kp] = pack2bf(Wsrc[(2 * kp) * DIM + n], Wsrc[(2 * kp + 1) * DIM + n]);
        }
        return;
    }
    if (t < NB) { hD[t] = 0; hS[t] = 0; }
    __syncthreads();
    int e0 = blockIdx.x * 1024 + t * 4;
    int s[4], d[4];
    bool v[4];
#pragma unroll
    for (int i = 0; i < 4; i++) {
        v[i] = (e0 + i) < E;
        s[i] = 0; d[i] = 0;
        if (v[i]) { s[i] = src[e0 + i]; d[i] = dst[e0 + i]; }
    }
#pragma unroll
    for (int i = 0; i < 4; i++) {
        if (v[i]) {
            atomicAdd(&hD[d[i] >> 11], 1);
            atomicAdd(&hS[s[i] >> 11], 1);
        }
    }
    __syncthreads();
    if (t < NB) {
        bD[t] = atomicAdd(&cntD[t], hD[t]);
        bS[t] = atomicAdd(&cntS[t], hS[t]);
        hD[t] = 0; hS[t] = 0;
    }
    __syncthreads();
#pragma unroll
    for (int i = 0; i < 4; i++) {
        if (v[i]) {
            int bd = d[i] >> 11;
            int r = atomicAdd(&hD[bd], 1);
            int idx = bD[bd] + r;
            if (idx < BCAP)
                binD[bd * BCAP + idx] = ((unsigned)(d[i] & 2047) << 17) | (unsigned)s[i];
            int bs = s[i] >> 11;
            int r2 = atomicAdd(&hS[bs], 1);
            int idx2 = bS[bs] + r2;
            if (idx2 < BCAP) binS[bs * BCAP + idx2] = (unsigned short)(s[i] & 2047);
        }
    }
}

// ===== k_mega: CSR-from-buckets + src-histogram + layer-1 MFMA GEMM (fp32 X -> bf16 frags) ======
// [0, NB*CSPLIT): CSR sub-blocks; [NB*CSPLIT, 2*NB*CSPLIT): out_cnt histogram; rest: GEMM1.
__global__ __launch_bounds__(256) void k_mega(const unsigned* __restrict__ binD,
                                              const unsigned short* __restrict__ binS,
                                              const int* __restrict__ cntD,
                                              const int* __restrict__ cntS,
                                              int* __restrict__ in_cnt,
                                              int* __restrict__ out_cnt,
                                              int* __restrict__ csr_pad,
                                              const float* __restrict__ x,
                                              const unsigned* __restrict__ wT1g,
                                              unsigned* __restrict__ xwb, int N,
                                              int NB) {
    __shared__ __align__(16) char smem[34816];  // union: wT 34 KB | counters 16 KB
    int bid = blockIdx.x;
    int t = threadIdx.x;

    if (bid < NB * CSPLIT) {
        // ---------- CSR build: sub-block `sub` of bucket `b` ----------
        int b = bid / CSPLIT;
        int sub = bid - b * CSPLIT;
        int* h = (int*)smem;             // 2048 local counters
        int* bArr = ((int*)smem) + 2048; // 2048 global base offsets
        for (int j = t; j < 2048; j += 256) h[j] = 0;
        __syncthreads();
        int base = b << 11;
        int nE = cntD[b];
        if (nE > BCAP) nE = BCAP;
        int chunk = (nE + CSPLIT - 1) / CSPLIT;
        int i0 = sub * chunk;
        int i1 = i0 + chunk;
        if (i1 > nE) i1 = nE;
        const unsigned* bb = &binD[b * BCAP];
        for (int i = i0 + t * 4; i < i1; i += 1024) {
            unsigned e[4];
            int k = i1 - i;
            if (k > 4) k = 4;
#pragma unroll
            for (int j = 0; j < 4; j++)
                if (j < k) e[j] = bb[i + j];
#pragma unroll
            for (int j = 0; j < 4; j++)
                if (j < k) atomicAdd(&h[e[j] >> 17], 1);
        }
        __syncthreads();
        for (int j = t; j < 2048; j += 256) {
            int hv = h[j];
            bArr[j] = hv ? atomicAdd(&in_cnt[base + j], hv) : 0;
            h[j] = 0;
        }
        __syncthreads();
        for (int i = i0 + t * 4; i < i1; i += 1024) {
            unsigned e[4];
            int k = i1 - i;
            if (k > 4) k = 4;
#pragma unroll
            for (int j = 0; j < 4; j++)
                if (j < k) e[j] = bb[i + j];
#pragma unroll
            for (int j = 0; j < 4; j++)
                if (j < k) {
                    int dl = (int)(e[j] >> 17);
                    int pos = bArr[dl] + atomicAdd(&h[dl], 1);
                    if (pos < CAP)
                        csr_pad[(size_t)(base + dl) * CAP + pos] = (int)(e[j] & 0x1FFFFu);
                }
        }
        return;
    }
    if (bid < 2 * NB * CSPLIT) {
        // ---------- out-degree histogram: sub-block of bucket ----------
        int bb2 = bid - NB * CSPLIT;
        int b = bb2 / CSPLIT;
        int sub = bb2 - b * CSPLIT;
        int* hist = (int*)smem;
        for (int j = t; j < 2048; j += 256) hist[j] = 0;
        __syncthreads();
        int base = b << 11;
        int nE = cntS[b];
        if (nE > BCAP) nE = BCAP;
        int chunk = (nE + CSPLIT - 1) / CSPLIT;
        int i0 = sub * chunk;
        int i1 = i0 + chunk;
        if (i1 > nE) i1 = nE;
        const unsigned short* bs = &binS[b * BCAP];
        for (int i = i0 + t * 4; i < i1; i += 1024) {
            unsigned short e[4];
            int k = i1 - i;
            if (k > 4) k = 4;
#pragma unroll
            for (int j = 0; j < 4; j++)
                if (j < k) e[j] = bs[i + j];
#pragma unroll
            for (int j = 0; j < 4; j++)
                if (j < k) atomicAdd(&hist[(int)e[j]], 1);
        }
        __syncthreads();
        for (int j = t; j < 2048; j += 256) {
            int hv = hist[j];
            if (hv) atomicAdd(&out_cnt[base + j], hv);
        }
        return;
    }
    // ---------- GEMM1 via MFMA: xwb = bf16(X @ W1) (unscaled) ----------
    int gb = bid - 2 * NB * CSPLIT;
    unsigned* wT = (unsigned*)smem;  // 128 rows x stride 68
#pragma unroll
    for (int i = 0; i < 8; i++) {
        int idx = t + i * 256;
        int row = idx >> 4;
        int col = idx & 15;
        *(uint4*)&wT[row * 68 + col * 4] = ((const uint4*)wT1g)[idx];
    }
    __syncthreads();
    int wave = t >> 6, lane = t & 63;
    int quad = lane >> 4, c = lane & 15;
    int m = gb * 64 + wave * 16 + c;
    bool mv = m < N;
    f32x4 acc[8];
#pragma unroll
    for (int i = 0; i < 8; i++) acc[i] = (f32x4){0.f, 0.f, 0.f, 0.f};

#pragma unroll
    for (int ks = 0; ks < 4; ks++) {
        U16 av;
        if (mv) {
            const float4* xr = (const float4*)&x[(size_t)m * DIM + ks * 32 + quad * 8];
            float4 f0 = xr[0], f1 = xr[1];
            av.u.x = pack2bf(f0.x, f0.y);
            av.u.y = pack2bf(f0.z, f0.w);
            av.u.z = pack2bf(f1.x, f1.y);
            av.u.w = pack2bf(f1.z, f1.w);
        } else {
            av.u = make_uint4(0, 0, 0, 0);
        }
#pragma unroll
        for (int cb = 0; cb < 8; cb++) {
            U16 bv;
            bv.u = *(const uint4*)&wT[(cb * 16 + c) * 68 + ks * 16 + quad * 4];
            acc[cb] = __builtin_amdgcn_mfma_f32_16x16x32_bf16(av.b, bv.b, acc[cb], 0, 0, 0);
        }
    }
    int rowBase = gb * 64 + wave * 16 + quad * 4;
#pragma unroll
    for (int r = 0; r < 4; r++) {
        int rowN = rowBase + r;
#pragma unroll
        for (int cb = 0; cb < 8; cb++) {
            float v = acc[cb][r];
            float vn = __shfl_xor(v, 1, 64);
            if (((c & 1) == 0) && rowN < N)
                xwb[rowN * 64 + cb * 8 + (c >> 1)] = pack2bf(v, vn);
        }
    }
}

// ---------------- k_nrm: precompute nsv[n] = rsqrt(out_deg+1) (R14; 400 KB, L2-resident) -------
__global__ __launch_bounds__(256) void k_nrm(const int* __restrict__ out_cnt,
                                             float* __restrict__ nsv, int N) {
    int i = (blockIdx.x * 256 + threadIdx.x) * 4;
    if (i + 3 < N) {
        int4 d = *(const int4*)&out_cnt[i];
        float4 r;
        r.x = rsqrtf((float)(d.x + 1));
        r.y = rsqrtf((float)(d.y + 1));
        r.z = rsqrtf((float)(d.z + 1));
        r.w = rsqrtf((float)(d.w + 1));
        *(float4*)&nsv[i] = r;
    } else {
        for (int j = i; j < N && j < i + 4; j++) nsv[j] = rsqrtf((float)(out_cnt[j] + 1));
    }
}

// ---------------- CSR aggregation, R14 structure: 4 nodes/wave, 16 lanes/node ------------------
// MODE 0: layer-1 (xwb unscaled; per-source scale nsv[s], final *ndv)
// MODE 1: layers 2/3 (xwb pre-scaled by nsrc; ndv folded into every FMA -> v_fma_mix eligible)
// MODE 2: MODE 1 + fused sigmoid gate
// Kills the old 16x ds_swizzle cross-quad reduce + predicated epilogue; accum via native-__bf16
// fmaf (v_fma_mix_f32_bf16 candidate); per-source rsqrt replaced by nsv broadcast load.
template <int MODE>
__device__ __forceinline__ void agg_body(const uint4* __restrict__ xwb4,
                                         const int* __restrict__ in_cnt,
                                         const int* __restrict__ csr_pad,
                                         const float* __restrict__ nsv,
                                         const float* __restrict__ bias,
                                         uint4* __restrict__ hb4,
                                         const float* __restrict__ Wp,
                                         const float* __restrict__ bp,
                                         float* __restrict__ wg, int N) {
    int wid = (blockIdx.x * 256 + threadIdx.x) >> 6;
    int lane = threadIdx.x & 63;
    int g = lane >> 4, c = lane & 15;
    int n = wid * 4 + g;
    bool nv = n < N;
    int deg_true = nv ? in_cnt[n] : 0;
    int deg = deg_true > CAP ? CAP : deg_true;
    float ndv = rsqrtf((float)(deg_true + 1));
    const int* row = csr_pad + (size_t)n * CAP;

    float acc[8];
#pragma unroll
    for (int i = 0; i < 8; i++) acc[i] = 0.f;

    if (nv) {
        float s0 = (MODE == 0) ? nsv[n] : ndv;
        accum8m(acc, xwb4[(size_t)n * 16 + c], s0);  // self-loop
    }
    for (int p = 0; p < deg; p += 4) {
        int sidx[4];
        uint4 gv[4];
        float sc[4];
        bool pv[4];
#pragma unroll
        for (int u = 0; u < 4; u++) {
            pv[u] = (p + u) < deg;
            sidx[u] = pv[u] ? row[p + u] : row[p];
        }
#pragma unroll
        for (int u = 0; u < 4; u++) gv[u] = xwb4[(size_t)sidx[u] * 16 + c];
#pragma unroll
        for (int u = 0; u < 4; u++) sc[u] = (MODE == 0) ? nsv[sidx[u]] : ndv;
#pragma unroll
        for (int u = 0; u < 4; u++)
            if (pv[u]) accum8m(acc, gv[u], sc[u]);
    }

    float mul = (MODE == 0) ? ndv : 1.f;
    float4 b0 = ((const float4*)bias)[2 * c];
    float4 b1 = ((const float4*)bias)[2 * c + 1];
    float o[8];
    o[0] = fmaxf(acc[0] * mul + b0.x, 0.f);
    o[1] = fmaxf(acc[1] * mul + b0.y, 0.f);
    o[2] = fmaxf(acc[2] * mul + b0.z, 0.f);
    o[3] = fmaxf(acc[3] * mul + b0.w, 0.f);
    o[4] = fmaxf(acc[4] * mul + b1.x, 0.f);
    o[5] = fmaxf(acc[5] * mul + b1.y, 0.f);
    o[6] = fmaxf(acc[6] * mul + b1.z, 0.f);
    o[7] = fmaxf(acc[7] * mul + b1.w, 0.f);
    if (nv) {
        uint4 w;
        w.x = pack2bf(o[0], o[1]);
        w.y = pack2bf(o[2], o[3]);
        w.z = pack2bf(o[4], o[5]);
        w.w = pack2bf(o[6], o[7]);
        hb4[(size_t)n * 16 + c] = w;
    }
    if (MODE == 2) {
        float4 w0 = ((const float4*)Wp)[2 * c];
        float4 w1 = ((const float4*)Wp)[2 * c + 1];
        float s = o[0] * w0.x + o[1] * w0.y + o[2] * w0.z + o[3] * w0.w +
                  o[4] * w1.x + o[5] * w1.y + o[6] * w1.z + o[7] * w1.w;
        s += __shfl_xor(s, 1, 64);
        s += __shfl_xor(s, 2, 64);
        s += __shfl_xor(s, 4, 64);
        s += __shfl_xor(s, 8, 64);
        if (nv && c == 0) wg[n] = 1.f / (1.f + expf(-(s + bp[0])));
    }
}

__global__ __launch_bounds__(256) void k_agg1(const uint4* __restrict__ xwb4,
                                              const int* __restrict__ in_cnt,
                                              const int* __restrict__ csr_pad,
                                              const float* __restrict__ nsv,
                                              const float* __restrict__ bias,
                                              uint4* __restrict__ hb4, int N) {
    agg_body<0>(xwb4, in_cnt, csr_pad, nsv, bias, hb4, nullptr, nullptr, nullptr, N);
}

__global__ __launch_bounds__(256) void k_agg(const uint4* __restrict__ xwb4,
                                             const int* __restrict__ in_cnt,
                                             const int* __restrict__ csr_pad,
                                             const float* __restrict__ bias,
                                             uint4* __restrict__ hb4, int N) {
    agg_body<1>(xwb4, in_cnt, csr_pad, nullptr, bias, hb4, nullptr, nullptr, nullptr, N);
}

__global__ __launch_bounds__(256) void k_agg_gate(const uint4* __restrict__ xwb4,
                                                  const int* __restrict__ in_cnt,
                                                  const int* __restrict__ csr_pad,
                                                  const float* __restrict__ bias,
                                                  uint4* __restrict__ hb4,
                                                  const float* __restrict__ Wp,
                                                  const float* __restrict__ bp,
                                                  float* __restrict__ wg, int N) {
    agg_body<2>(xwb4, in_cnt, csr_pad, nullptr, bias, hb4, Wp, bp, wg, N);
}

// ---------------- MFMA GEMM (packed-bf16 input, prepacked W^T): xwb = bf16(nsrc .* (H@W)) -------
__global__ __launch_bounds__(256) void k_xw_mfma(const unsigned* __restrict__ hb,
                                                 const int* __restrict__ out_cnt,
                                                 const unsigned* __restrict__ wTg,
                                                 unsigned* __restrict__ xwb, int N) {
    __shared__ unsigned wT[128 * 68];
    int t = threadIdx.x;
#pragma unroll
    for (int i = 0; i < 8; i++) {
        int idx = t + i * 256;
        int row = idx >> 4;
        int col = idx & 15;
        *(uint4*)&wT[row * 68 + col * 4] = ((const uint4*)wTg)[idx];
    }
    __syncthreads();
    int wave = t >> 6, lane = t & 63;
    int quad = lane >> 4, c = lane & 15;
    int m = blockIdx.x * 64 + wave * 16 + c;
    bool mv = m < N;
    f32x4 acc[8];
#pragma unroll
    for (int i = 0; i < 8; i++) acc[i] = (f32x4){0.f, 0.f, 0.f, 0.f};

#pragma unroll
    for (int ks = 0; ks < 4; ks++) {
        U16 av;
        if (mv) av.u = *(const uint4*)&hb[m * 64 + ks * 16 + quad * 4];
        else av.u = make_uint4(0, 0, 0, 0);
#pragma unroll
        for (int cb = 0; cb < 8; cb++) {
            U16 bv;
            bv.u = *(const uint4*)&wT[(cb * 16 + c) * 68 + ks * 16 + quad * 4];
            acc[cb] = __builtin_amdgcn_mfma_f32_16x16x32_bf16(av.b, bv.b, acc[cb], 0, 0, 0);
        }
    }
    int rowBase = blockIdx.x * 64 + wave * 16 + quad * 4;
#pragma unroll
    for (int r = 0; r < 4; r++) {
        int rowN = rowBase + r;
        float nrm = (rowN < N) ? rsqrtf((float)(out_cnt[rowN] + 1)) : 0.f;
#pragma unroll
        for (int cb = 0; cb < 8; cb++) {
            float v = acc[cb][r] * nrm;
            float vn = __shfl_xor(v, 1, 64);
            if (((c & 1) == 0) && rowN < N)
                xwb[rowN * 64 + cb * 8 + (c >> 1)] = pack2bf(v, vn);
        }
    }
}

// ---------------- pooling: weighted sum + max per graph ----------------
__device__ __forceinline__ int lower_bound(const int* a, int n, int key) {
    int lo = 0, hi = n;
    while (lo < hi) {
        int m = (lo + hi) >> 1;
        if (a[m] < key) lo = m + 1;
        else hi = m;
    }
    return lo;
}

__global__ __launch_bounds__(64) void k_pool(const unsigned* __restrict__ hb,
                                             const float* __restrict__ wg,
                                             const int* __restrict__ gids,
                                             float* __restrict__ out, int N) {
    int g = blockIdx.x >> 4;
    int part = blockIdx.x & 15;
    int t = threadIdx.x;
    int start = lower_bound(gids, N, g);
    int end = lower_bound(gids, N, g + 1);
    float2 sum = {0.f, 0.f}, mx = {0.f, 0.f};
    for (int n = start + part; n < end; n += 16) {
        float w = wg[n];
        float2 v = unpack2bf(hb[n * 64 + t]);
        sum.x += v.x * w;
        sum.y += v.y * w;
        mx.x = fmaxf(mx.x, v.x);
        mx.y = fmaxf(mx.y, v.y);
    }
    atomicAdd(&out[g * 256 + 2 * t], sum.x);
    atomicAdd(&out[g * 256 + 2 * t + 1], sum.y);
    atomicMax((int*)&out[g * 256 + 128 + 2 * t], __float_as_int(mx.x));
    atomicMax((int*)&out[g * 256 + 128 + 2 * t + 1], __float_as_int(mx.y));
}

extern "C" void kernel_launch(void* const* d_in, const int* in_sizes, int n_in,
                              void* d_out, int out_size, void* d_ws, size_t ws_size,
                              hipStream_t stream) {
    const float* node_feats = (const float*)d_in[0];
    const int* src = (const int*)d_in[1];
    const int* dst = (const int*)d_in[2];
    const int* gids = (const int*)d_in[3];
    const float* W1 = (const float*)d_in[4];
    const float* b1 = (const float*)d_in[5];
    const float* W2 = (const float*)d_in[6];
    const float* b2 = (const float*)d_in[7];
    const float* W3 = (const float*)d_in[8];
    const float* b3 = (const float*)d_in[9];
    const float* Wp = (const float*)d_in[10];
    const float* bp = (const float*)d_in[11];
    float* out = (float*)d_out;

    const int N = in_sizes[3];
    const int E = in_sizes[1];
    const int G = out_size / 256;
    const int NB = (N + 2047) >> 11;   // buckets of 2048 nodes (<= NBMAX)

    // ---- workspace layout (bytes) ----
    char* ws = (char*)d_ws;
    size_t o = 0;
    int* cntD = (int*)(ws + o);          o += NBMAX * 4;   // zeroed
    int* cntS = (int*)(ws + o);          o += NBMAX * 4;   // zeroed
    int* in_cnt = (int*)(ws + o);        o += (size_t)N * 4;   // zeroed; atomically built by k_mega
    int* out_cnt = (int*)(ws + o);       o += (size_t)N * 4;   // zeroed; atomically built by k_mega
    size_t zero_bytes = o;
    float* wg = (float*)(ws + o);        o += (size_t)N * 4;
    float* nsv = (float*)(ws + o);       o += (size_t)N * 4;   // rsqrt(out_deg+1), k_nrm (R14)
    o = (o + 15) & ~15ull;
    unsigned* wT1g = (unsigned*)(ws + o); o += 8192 * 4;
    unsigned* wT2g = (unsigned*)(ws + o); o += 8192 * 4;
    unsigned* wT3g = (unsigned*)(ws + o); o += 8192 * 4;
    unsigned* binD = (unsigned*)(ws + o); o += (size_t)NBMAX * BCAP * 4;
    unsigned short* binS = (unsigned short*)(ws + o); o += (size_t)NBMAX * BCAP * 2;
    o = (o + 15) & ~15ull;
    int* csr_pad = (int*)(ws + o);       o += (size_t)N * CAP * 4;
    unsigned* xwb = (unsigned*)(ws + o); o += (size_t)N * 64 * 4;
    unsigned* hb = (unsigned*)(ws + o);  o += (size_t)N * 64 * 4;
    (void)ws_size;

    (void)hipMemsetAsync(d_ws, 0, zero_bytes, stream);
    (void)hipMemsetAsync(d_out, 0, (size_t)out_size * 4, stream);

    int binGrid = (E + 1023) / 1024;
    int mmGrid = (N + 63) / 64;
    int aggGrid = (N + 15) / 16;      // 4 nodes/wave, 4 waves/block (R14)
    int nrmGrid = (N + 1023) / 1024;

    // Phase 1: bucket edges + W1/W2/W3 bf16-transpose prepack (3 tail blocks)
    k_bin<<<binGrid + 3, 256, 0, stream>>>(src, dst, E, binD, binS, cntD, cntS, NB, binGrid,
                                           W1, W2, W3, wT1g, wT2g, wT3g);
    // Phase 2: CSR-from-buckets (CSPLIT-way) + out-degree histogram + layer-1 MFMA GEMM
    k_mega<<<2 * NB * CSPLIT + mmGrid, 256, 0, stream>>>(binD, binS, cntD, cntS, in_cnt,
                                                         out_cnt, csr_pad, node_feats,
                                                         wT1g, xwb, N, NB);
    // nsv = rsqrt(out_deg+1) once (replaces per-source cvt+rsq in k_agg1)
    k_nrm<<<nrmGrid, 256, 0, stream>>>(out_cnt, nsv, N);
    // layer-1 aggregation (applies nsrc per source inline): xwb -> h1 (hb)
    k_agg1<<<aggGrid, 256, 0, stream>>>((const uint4*)xwb, in_cnt, csr_pad, nsv, b1,
                                        (uint4*)hb, N);
    // layer 2
    k_xw_mfma<<<mmGrid, 256, 0, stream>>>(hb, out_cnt, wT2g, xwb, N);
    k_agg<<<aggGrid, 256, 0, stream>>>((const uint4*)xwb, in_cnt, csr_pad, b2,
                                       (uint4*)hb, N);
    // layer 3 (+ fused sigmoid gate)
    k_xw_mfma<<<mmGrid, 256, 0, stream>>>(hb, out_cnt, wT3g, xwb, N);
    k_agg_gate<<<aggGrid, 256, 0, stream>>>((const uint4*)xwb, in_cnt, csr_pad, b3,
                                            (uint4*)hb, Wp, bp, wg, N);
    // pooling
    k_pool<<<G * 16, 64, 0, stream>>>(hb, wg, gids, out, N);
}

// Round 3
// 444.833 us; speedup vs baseline: 1.0261x; 1.0261x over previous
//
#include <hip/hip_runtime.h>
#include <hip/hip_bf16.h>

#define DIM 128
#define CAP 64       // padded CSR row capacity; in-deg ~Poisson(16), P(>=64) astronomically small
#define NBMAX 64     // max buckets (node-space / 2048)
#define BCAP 36864   // per-bucket edge capacity; mean ~32.7k, +22 sigma margin
#define CSPLIT 8     // sub-blocks per bucket for CSR/hist build (straggler fix, R13)

typedef __attribute__((ext_vector_type(8))) short bf16x8;
typedef __attribute__((ext_vector_type(4))) float f32x4;
typedef __bf16 bf16x2 __attribute__((ext_vector_type(2)));
union U16 { uint4 u; bf16x8 b; };
union UB { unsigned u; bf16x2 h; };

// ---- bf16 pack/unpack helpers (manual, RNE) ----
__device__ __forceinline__ unsigned short f2bf(float f) {
    unsigned u = __float_as_uint(f);
    unsigned r = (u + 0x7fffu + ((u >> 16) & 1u)) >> 16;
    return (unsigned short)r;
}
__device__ __forceinline__ unsigned pack2bf(float a, float b) {
    return (unsigned)f2bf(a) | ((unsigned)f2bf(b) << 16);
}
__device__ __forceinline__ float2 unpack2bf(unsigned v) {
    float2 r;
    r.x = __uint_as_float(v << 16);
    r.y = __uint_as_float(v & 0xffff0000u);
    return r;
}
__device__ __forceinline__ void accum8s(float* acc, uint4 v, float s) {
    float2 f0 = unpack2bf(v.x), f1 = unpack2bf(v.y);
    float2 f2 = unpack2bf(v.z), f3 = unpack2bf(v.w);
    acc[0] += s * f0.x; acc[1] += s * f0.y; acc[2] += s * f1.x; acc[3] += s * f1.y;
    acc[4] += s * f2.x; acc[5] += s * f2.y; acc[6] += s * f3.x; acc[7] += s * f3.y;
}
// R14: native-__bf16 extraction + fmaf -> eligible for gfx950 v_fma_mix_f32_bf16.
__device__ __forceinline__ void accum8m(float* acc, uint4 v, float s) {
    UB w0, w1, w2, w3;
    w0.u = v.x; w1.u = v.y; w2.u = v.z; w3.u = v.w;
    acc[0] = fmaf((float)w0.h[0], s, acc[0]);
    acc[1] = fmaf((float)w0.h[1], s, acc[1]);
    acc[2] = fmaf((float)w1.h[0], s, acc[2]);
    acc[3] = fmaf((float)w1.h[1], s, acc[3]);
    acc[4] = fmaf((float)w2.h[0], s, acc[4]);
    acc[5] = fmaf((float)w2.h[1], s, acc[5]);
    acc[6] = fmaf((float)w3.h[0], s, acc[6]);
    acc[7] = fmaf((float)w3.h[1], s, acc[7]);
}

// ================= k_bin: bucket edges (R12-verified) + W1/W2/W3 bf16-T prepack tail ============
__global__ __launch_bounds__(256) void k_bin(const int* __restrict__ src,
                                             const int* __restrict__ dst, int E,
                                             unsigned* __restrict__ binD,
                                             unsigned short* __restrict__ binS,
                                             int* __restrict__ cntD,
                                             int* __restrict__ cntS, int NB, int binGrid,
                                             const float* __restrict__ W1,
                                             const float* __restrict__ W2,
                                             const float* __restrict__ W3,
                                             unsigned* __restrict__ wT1g,
                                             unsigned* __restrict__ wT2g,
                                             unsigned* __restrict__ wT3g) {
    __shared__ int hD[NBMAX], hS[NBMAX], bD[NBMAX], bS[NBMAX];
    int t = threadIdx.x;
    if ((int)blockIdx.x >= binGrid) {
        // ---------- W^T bf16 prepack: wTg[n*64+kp] = pack(W[2kp][n], W[2kp+1][n]) ----------
        int w = blockIdx.x - binGrid;
        const float* Wsrc = (w == 0) ? W1 : (w == 1) ? W2 : W3;
        unsigned* wTg = (w == 0) ? wT1g : (w == 1) ? wT2g : wT3g;
        int n = t >> 1;
        int kp0 = (t & 1) * 32;
#pragma unroll
        for (int i = 0; i < 32; i++) {
            int kp = kp0 + i;
            wTg[n * 64 + kp] = pack2bf(Wsrc[(2 * kp) * DIM + n], Wsrc[(2 * kp + 1) * DIM + n]);
        }
        return;
    }
    if (t < NB) { hD[t] = 0; hS[t] = 0; }
    __syncthreads();
    int e0 = blockIdx.x * 1024 + t * 4;
    int s[4], d[4];
    bool v[4];
#pragma unroll
    for (int i = 0; i < 4; i++) {
        v[i] = (e0 + i) < E;
        s[i] = 0; d[i] = 0;
        if (v[i]) { s[i] = src[e0 + i]; d[i] = dst[e0 + i]; }
    }
#pragma unroll
    for (int i = 0; i < 4; i++) {
        if (v[i]) {
            atomicAdd(&hD[d[i] >> 11], 1);
            atomicAdd(&hS[s[i] >> 11], 1);
        }
    }
    __syncthreads();
    if (t < NB) {
        bD[t] = atomicAdd(&cntD[t], hD[t]);
        bS[t] = atomicAdd(&cntS[t], hS[t]);
        hD[t] = 0; hS[t] = 0;
    }
    __syncthreads();
#pragma unroll
    for (int i = 0; i < 4; i++) {
        if (v[i]) {
            int bd = d[i] >> 11;
            int r = atomicAdd(&hD[bd], 1);
            int idx = bD[bd] + r;
            if (idx < BCAP)
                binD[bd * BCAP + idx] = ((unsigned)(d[i] & 2047) << 17) | (unsigned)s[i];
            int bs = s[i] >> 11;
            int r2 = atomicAdd(&hS[bs], 1);
            int idx2 = bS[bs] + r2;
            if (idx2 < BCAP) binS[bs * BCAP + idx2] = (unsigned short)(s[i] & 2047);
        }
    }
}

// ===== k_mega: CSR-from-buckets + src-histogram + layer-1 MFMA GEMM (fp32 X -> bf16 frags) ======
// [0, NB*CSPLIT): CSR sub-blocks; [NB*CSPLIT, 2*NB*CSPLIT): out_cnt histogram; rest: GEMM1.
__global__ __launch_bounds__(256) void k_mega(const unsigned* __restrict__ binD,
                                              const unsigned short* __restrict__ binS,
                                              const int* __restrict__ cntD,
                                              const int* __restrict__ cntS,
                                              int* __restrict__ in_cnt,
                                              int* __restrict__ out_cnt,
                                              int* __restrict__ csr_pad,
                                              const float* __restrict__ x,
                                              const unsigned* __restrict__ wT1g,
                                              unsigned* __restrict__ xwb, int N,
                                              int NB) {
    __shared__ __align__(16) char smem[34816];  // union: wT 34 KB | counters 16 KB
    int bid = blockIdx.x;
    int t = threadIdx.x;

    if (bid < NB * CSPLIT) {
        // ---------- CSR build: sub-block `sub` of bucket `b` ----------
        int b = bid / CSPLIT;
        int sub = bid - b * CSPLIT;
        int* h = (int*)smem;             // 2048 local counters
        int* bArr = ((int*)smem) + 2048; // 2048 global base offsets
        for (int j = t; j < 2048; j += 256) h[j] = 0;
        __syncthreads();
        int base = b << 11;
        int nE = cntD[b];
        if (nE > BCAP) nE = BCAP;
        int chunk = (nE + CSPLIT - 1) / CSPLIT;
        int i0 = sub * chunk;
        int i1 = i0 + chunk;
        if (i1 > nE) i1 = nE;
        const unsigned* bb = &binD[b * BCAP];
        for (int i = i0 + t * 4; i < i1; i += 1024) {
            unsigned e[4];
            int k = i1 - i;
            if (k > 4) k = 4;
#pragma unroll
            for (int j = 0; j < 4; j++)
                if (j < k) e[j] = bb[i + j];
#pragma unroll
            for (int j = 0; j < 4; j++)
                if (j < k) atomicAdd(&h[e[j] >> 17], 1);
        }
        __syncthreads();
        for (int j = t; j < 2048; j += 256) {
            int hv = h[j];
            bArr[j] = hv ? atomicAdd(&in_cnt[base + j], hv) : 0;
            h[j] = 0;
        }
        __syncthreads();
        for (int i = i0 + t * 4; i < i1; i += 1024) {
            unsigned e[4];
            int k = i1 - i;
            if (k > 4) k = 4;
#pragma unroll
            for (int j = 0; j < 4; j++)
                if (j < k) e[j] = bb[i + j];
#pragma unroll
            for (int j = 0; j < 4; j++)
                if (j < k) {
                    int dl = (int)(e[j] >> 17);
                    int pos = bArr[dl] + atomicAdd(&h[dl], 1);
                    if (pos < CAP)
                        csr_pad[(size_t)(base + dl) * CAP + pos] = (int)(e[j] & 0x1FFFFu);
                }
        }
        return;
    }
    if (bid < 2 * NB * CSPLIT) {
        // ---------- out-degree histogram: sub-block of bucket ----------
        int bb2 = bid - NB * CSPLIT;
        int b = bb2 / CSPLIT;
        int sub = bb2 - b * CSPLIT;
        int* hist = (int*)smem;
        for (int j = t; j < 2048; j += 256) hist[j] = 0;
        __syncthreads();
        int base = b << 11;
        int nE = cntS[b];
        if (nE > BCAP) nE = BCAP;
        int chunk = (nE + CSPLIT - 1) / CSPLIT;
        int i0 = sub * chunk;
        int i1 = i0 + chunk;
        if (i1 > nE) i1 = nE;
        const unsigned short* bs = &binS[b * BCAP];
        for (int i = i0 + t * 4; i < i1; i += 1024) {
            unsigned short e[4];
            int k = i1 - i;
            if (k > 4) k = 4;
#pragma unroll
            for (int j = 0; j < 4; j++)
                if (j < k) e[j] = bs[i + j];
#pragma unroll
            for (int j = 0; j < 4; j++)
                if (j < k) atomicAdd(&hist[(int)e[j]], 1);
        }
        __syncthreads();
        for (int j = t; j < 2048; j += 256) {
            int hv = hist[j];
            if (hv) atomicAdd(&out_cnt[base + j], hv);
        }
        return;
    }
    // ---------- GEMM1 via MFMA: xwb = bf16(X @ W1) (unscaled) ----------
    int gb = bid - 2 * NB * CSPLIT;
    unsigned* wT = (unsigned*)smem;  // 128 rows x stride 68
#pragma unroll
    for (int i = 0; i < 8; i++) {
        int idx = t + i * 256;
        int row = idx >> 4;
        int col = idx & 15;
        *(uint4*)&wT[row * 68 + col * 4] = ((const uint4*)wT1g)[idx];
    }
    __syncthreads();
    int wave = t >> 6, lane = t & 63;
    int quad = lane >> 4, c = lane & 15;
    int m = gb * 64 + wave * 16 + c;
    bool mv = m < N;
    f32x4 acc[8];
#pragma unroll
    for (int i = 0; i < 8; i++) acc[i] = (f32x4){0.f, 0.f, 0.f, 0.f};

#pragma unroll
    for (int ks = 0; ks < 4; ks++) {
        U16 av;
        if (mv) {
            const float4* xr = (const float4*)&x[(size_t)m * DIM + ks * 32 + quad * 8];
            float4 f0 = xr[0], f1 = xr[1];
            av.u.x = pack2bf(f0.x, f0.y);
            av.u.y = pack2bf(f0.z, f0.w);
            av.u.z = pack2bf(f1.x, f1.y);
            av.u.w = pack2bf(f1.z, f1.w);
        } else {
            av.u = make_uint4(0, 0, 0, 0);
        }
#pragma unroll
        for (int cb = 0; cb < 8; cb++) {
            U16 bv;
            bv.u = *(const uint4*)&wT[(cb * 16 + c) * 68 + ks * 16 + quad * 4];
            acc[cb] = __builtin_amdgcn_mfma_f32_16x16x32_bf16(av.b, bv.b, acc[cb], 0, 0, 0);
        }
    }
    int rowBase = gb * 64 + wave * 16 + quad * 4;
#pragma unroll
    for (int r = 0; r < 4; r++) {
        int rowN = rowBase + r;
#pragma unroll
        for (int cb = 0; cb < 8; cb++) {
            float v = acc[cb][r];
            float vn = __shfl_xor(v, 1, 64);
            if (((c & 1) == 0) && rowN < N)
                xwb[rowN * 64 + cb * 8 + (c >> 1)] = pack2bf(v, vn);
        }
    }
}

// ---------------- k_nrm: precompute nsv[n] = rsqrt(out_deg+1) (R14; 400 KB, L2-resident) -------
__global__ __launch_bounds__(256) void k_nrm(const int* __restrict__ out_cnt,
                                             float* __restrict__ nsv, int N) {
    int i = (blockIdx.x * 256 + threadIdx.x) * 4;
    if (i + 3 < N) {
        int4 d = *(const int4*)&out_cnt[i];
        float4 r;
        r.x = rsqrtf((float)(d.x + 1));
        r.y = rsqrtf((float)(d.y + 1));
        r.z = rsqrtf((float)(d.z + 1));
        r.w = rsqrtf((float)(d.w + 1));
        *(float4*)&nsv[i] = r;
    } else {
        for (int j = i; j < N && j < i + 4; j++) nsv[j] = rsqrtf((float)(out_cnt[j] + 1));
    }
}

// ---------------- CSR aggregation, R15: 4 nodes/wave, deep-batch-16 gather ---------------------
// R15: R14's VALU cut was time-neutral (VALUBusy 63->31%, dur unchanged) => latency-bound.
// Fix: issue 16 gathers per batch BEFORE any accumulation (4x in-flight loads/wave).
// Invalid slots (p+u >= deg) redirect to the node's own row (L1-hot, no HBM traffic) with
// scale 0 -> uniform control flow, no exec-mask dance, no traffic waste.
// MODE 0: layer-1 (xwb unscaled; per-source scale nsv[s], final *ndv)
// MODE 1: layers 2/3 (xwb pre-scaled by nsrc; ndv folded into every FMA)
// MODE 2: MODE 1 + fused sigmoid gate
template <int MODE>
__device__ __forceinline__ void agg_body(const uint4* __restrict__ xwb4,
                                         const int* __restrict__ in_cnt,
                                         const int* __restrict__ csr_pad,
                                         const float* __restrict__ nsv,
                                         const float* __restrict__ bias,
                                         uint4* __restrict__ hb4,
                                         const float* __restrict__ Wp,
                                         const float* __restrict__ bp,
                                         float* __restrict__ wg, int N) {
    int wid = (blockIdx.x * 256 + threadIdx.x) >> 6;
    int lane = threadIdx.x & 63;
    int g = lane >> 4, c = lane & 15;
    int n = wid * 4 + g;
    bool nv = n < N;
    int deg_true = nv ? in_cnt[n] : 0;
    int deg = deg_true > CAP ? CAP : deg_true;
    float ndv = rsqrtf((float)(deg_true + 1));
    const int* row = csr_pad + (size_t)n * CAP;

    float acc[8];
#pragma unroll
    for (int i = 0; i < 8; i++) acc[i] = 0.f;

    if (nv) {
        float s0 = (MODE == 0) ? nsv[n] : ndv;
        accum8m(acc, xwb4[(size_t)n * 16 + c], s0);  // self-loop
    }
    for (int p = 0; p < deg; p += 16) {
        // slab-load 16 indices (uniform addr within 16-lane group -> HW broadcast);
        // reading past deg inside the CAP-padded row is in-bounds (garbage never used).
        int4 r0 = *(const int4*)&row[p];
        int4 r1 = *(const int4*)&row[p + 4];
        int4 r2 = *(const int4*)&row[p + 8];
        int4 r3 = *(const int4*)&row[p + 12];
        int sidx[16];
        sidx[0] = r0.x;  sidx[1] = r0.y;  sidx[2] = r0.z;  sidx[3] = r0.w;
        sidx[4] = r1.x;  sidx[5] = r1.y;  sidx[6] = r1.z;  sidx[7] = r1.w;
        sidx[8] = r2.x;  sidx[9] = r2.y;  sidx[10] = r2.z; sidx[11] = r2.w;
        sidx[12] = r3.x; sidx[13] = r3.y; sidx[14] = r3.z; sidx[15] = r3.w;
        uint4 gv[16];
        float sc[16];
#pragma unroll
        for (int u = 0; u < 16; u++) {
            bool pv = (p + u) < deg;
            int s = pv ? sidx[u] : n;                 // invalid -> own row (cache-hot)
            gv[u] = xwb4[(size_t)s * 16 + c];
            if (MODE == 0)
                sc[u] = pv ? nsv[s] : 0.f;
            else
                sc[u] = pv ? ndv : 0.f;
        }
#pragma unroll
        for (int u = 0; u < 16; u++) accum8m(acc, gv[u], sc[u]);
    }

    float mul = (MODE == 0) ? ndv : 1.f;
    float4 b0 = ((const float4*)bias)[2 * c];
    float4 b1 = ((const float4*)bias)[2 * c + 1];
    float o[8];
    o[0] = fmaxf(acc[0] * mul + b0.x, 0.f);
    o[1] = fmaxf(acc[1] * mul + b0.y, 0.f);
    o[2] = fmaxf(acc[2] * mul + b0.z, 0.f);
    o[3] = fmaxf(acc[3] * mul + b0.w, 0.f);
    o[4] = fmaxf(acc[4] * mul + b1.x, 0.f);
    o[5] = fmaxf(acc[5] * mul + b1.y, 0.f);
    o[6] = fmaxf(acc[6] * mul + b1.z, 0.f);
    o[7] = fmaxf(acc[7] * mul + b1.w, 0.f);
    if (nv) {
        uint4 w;
        w.x = pack2bf(o[0], o[1]);
        w.y = pack2bf(o[2], o[3]);
        w.z = pack2bf(o[4], o[5]);
        w.w = pack2bf(o[6], o[7]);
        hb4[(size_t)n * 16 + c] = w;
    }
    if (MODE == 2) {
        float4 w0 = ((const float4*)Wp)[2 * c];
        float4 w1 = ((const float4*)Wp)[2 * c + 1];
        float s = o[0] * w0.x + o[1] * w0.y + o[2] * w0.z + o[3] * w0.w +
                  o[4] * w1.x + o[5] * w1.y + o[6] * w1.z + o[7] * w1.w;
        s += __shfl_xor(s, 1, 64);
        s += __shfl_xor(s, 2, 64);
        s += __shfl_xor(s, 4, 64);
        s += __shfl_xor(s, 8, 64);
        if (nv && c == 0) wg[n] = 1.f / (1.f + expf(-(s + bp[0])));
    }
}

__global__ __launch_bounds__(256) void k_agg1(const uint4* __restrict__ xwb4,
                                              const int* __restrict__ in_cnt,
                                              const int* __restrict__ csr_pad,
                                              const float* __restrict__ nsv,
                                              const float* __restrict__ bias,
                                              uint4* __restrict__ hb4, int N) {
    agg_body<0>(xwb4, in_cnt, csr_pad, nsv, bias, hb4, nullptr, nullptr, nullptr, N);
}

__global__ __launch_bounds__(256) void k_agg(const uint4* __restrict__ xwb4,
                                             const int* __restrict__ in_cnt,
                                             const int* __restrict__ csr_pad,
                                             const float* __restrict__ bias,
                                             uint4* __restrict__ hb4, int N) {
    agg_body<1>(xwb4, in_cnt, csr_pad, nullptr, bias, hb4, nullptr, nullptr, nullptr, N);
}

__global__ __launch_bounds__(256) void k_agg_gate(const uint4* __restrict__ xwb4,
                                                  const int* __restrict__ in_cnt,
                                                  const int* __restrict__ csr_pad,
                                                  const float* __restrict__ bias,
                                                  uint4* __restrict__ hb4,
                                                  const float* __restrict__ Wp,
                                                  const float* __restrict__ bp,
                                                  float* __restrict__ wg, int N) {
    agg_body<2>(xwb4, in_cnt, csr_pad, nullptr, bias, hb4, Wp, bp, wg, N);
}

// ---------------- MFMA GEMM (packed-bf16 input, prepacked W^T): xwb = bf16(nsrc .* (H@W)) -------
__global__ __launch_bounds__(256) void k_xw_mfma(const unsigned* __restrict__ hb,
                                                 const int* __restrict__ out_cnt,
                                                 const unsigned* __restrict__ wTg,
                                                 unsigned* __restrict__ xwb, int N) {
    __shared__ unsigned wT[128 * 68];
    int t = threadIdx.x;
#pragma unroll
    for (int i = 0; i < 8; i++) {
        int idx = t + i * 256;
        int row = idx >> 4;
        int col = idx & 15;
        *(uint4*)&wT[row * 68 + col * 4] = ((const uint4*)wTg)[idx];
    }
    __syncthreads();
    int wave = t >> 6, lane = t & 63;
    int quad = lane >> 4, c = lane & 15;
    int m = blockIdx.x * 64 + wave * 16 + c;
    bool mv = m < N;
    f32x4 acc[8];
#pragma unroll
    for (int i = 0; i < 8; i++) acc[i] = (f32x4){0.f, 0.f, 0.f, 0.f};

#pragma unroll
    for (int ks = 0; ks < 4; ks++) {
        U16 av;
        if (mv) av.u = *(const uint4*)&hb[m * 64 + ks * 16 + quad * 4];
        else av.u = make_uint4(0, 0, 0, 0);
#pragma unroll
        for (int cb = 0; cb < 8; cb++) {
            U16 bv;
            bv.u = *(const uint4*)&wT[(cb * 16 + c) * 68 + ks * 16 + quad * 4];
            acc[cb] = __builtin_amdgcn_mfma_f32_16x16x32_bf16(av.b, bv.b, acc[cb], 0, 0, 0);
        }
    }
    int rowBase = blockIdx.x * 64 + wave * 16 + quad * 4;
#pragma unroll
    for (int r = 0; r < 4; r++) {
        int rowN = rowBase + r;
        float nrm = (rowN < N) ? rsqrtf((float)(out_cnt[rowN] + 1)) : 0.f;
#pragma unroll
        for (int cb = 0; cb < 8; cb++) {
            float v = acc[cb][r] * nrm;
            float vn = __shfl_xor(v, 1, 64);
            if (((c & 1) == 0) && rowN < N)
                xwb[rowN * 64 + cb * 8 + (c >> 1)] = pack2bf(v, vn);
        }
    }
}

// ---------------- pooling: weighted sum + max per graph ----------------
__device__ __forceinline__ int lower_bound(const int* a, int n, int key) {
    int lo = 0, hi = n;
    while (lo < hi) {
        int m = (lo + hi) >> 1;
        if (a[m] < key) lo = m + 1;
        else hi = m;
    }
    return lo;
}

__global__ __launch_bounds__(64) void k_pool(const unsigned* __restrict__ hb,
                                             const float* __restrict__ wg,
                                             const int* __restrict__ gids,
                                             float* __restrict__ out, int N) {
    int g = blockIdx.x >> 4;
    int part = blockIdx.x & 15;
    int t = threadIdx.x;
    int start = lower_bound(gids, N, g);
    int end = lower_bound(gids, N, g + 1);
    float2 sum = {0.f, 0.f}, mx = {0.f, 0.f};
    for (int n = start + part; n < end; n += 16) {
        float w = wg[n];
        float2 v = unpack2bf(hb[n * 64 + t]);
        sum.x += v.x * w;
        sum.y += v.y * w;
        mx.x = fmaxf(mx.x, v.x);
        mx.y = fmaxf(mx.y, v.y);
    }
    atomicAdd(&out[g * 256 + 2 * t], sum.x);
    atomicAdd(&out[g * 256 + 2 * t + 1], sum.y);
    atomicMax((int*)&out[g * 256 + 128 + 2 * t], __float_as_int(mx.x));
    atomicMax((int*)&out[g * 256 + 128 + 2 * t + 1], __float_as_int(mx.y));
}

extern "C" void kernel_launch(void* const* d_in, const int* in_sizes, int n_in,
                              void* d_out, int out_size, void* d_ws, size_t ws_size,
                              hipStream_t stream) {
    const float* node_feats = (const float*)d_in[0];
    const int* src = (const int*)d_in[1];
    const int* dst = (const int*)d_in[2];
    const int* gids = (const int*)d_in[3];
    const float* W1 = (const float*)d_in[4];
    const float* b1 = (const float*)d_in[5];
    const float* W2 = (const float*)d_in[6];
    const float* b2 = (const float*)d_in[7];
    const float* W3 = (const float*)d_in[8];
    const float* b3 = (const float*)d_in[9];
    const float* Wp = (const float*)d_in[10];
    const float* bp = (const float*)d_in[11];
    float* out = (float*)d_out;

    const int N = in_sizes[3];
    const int E = in_sizes[1];
    const int G = out_size / 256;
    const int NB = (N + 2047) >> 11;   // buckets of 2048 nodes (<= NBMAX)

    // ---- workspace layout (bytes) ----
    char* ws = (char*)d_ws;
    size_t o = 0;
    int* cntD = (int*)(ws + o);          o += NBMAX * 4;   // zeroed
    int* cntS = (int*)(ws + o);          o += NBMAX * 4;   // zeroed
    int* in_cnt = (int*)(ws + o);        o += (size_t)N * 4;   // zeroed; atomically built by k_mega
    int* out_cnt = (int*)(ws + o);       o += (size_t)N * 4;   // zeroed; atomically built by k_mega
    size_t zero_bytes = o;
    float* wg = (float*)(ws + o);        o += (size_t)N * 4;
    float* nsv = (float*)(ws + o);       o += (size_t)N * 4;   // rsqrt(out_deg+1), k_nrm (R14)
    o = (o + 15) & ~15ull;
    unsigned* wT1g = (unsigned*)(ws + o); o += 8192 * 4;
    unsigned* wT2g = (unsigned*)(ws + o); o += 8192 * 4;
    unsigned* wT3g = (unsigned*)(ws + o); o += 8192 * 4;
    unsigned* binD = (unsigned*)(ws + o); o += (size_t)NBMAX * BCAP * 4;
    unsigned short* binS = (unsigned short*)(ws + o); o += (size_t)NBMAX * BCAP * 2;
    o = (o + 15) & ~15ull;
    int* csr_pad = (int*)(ws + o);       o += (size_t)N * CAP * 4;
    unsigned* xwb = (unsigned*)(ws + o); o += (size_t)N * 64 * 4;
    unsigned* hb = (unsigned*)(ws + o);  o += (size_t)N * 64 * 4;
    (void)ws_size;

    (void)hipMemsetAsync(d_ws, 0, zero_bytes, stream);
    (void)hipMemsetAsync(d_out, 0, (size_t)out_size * 4, stream);

    int binGrid = (E + 1023) / 1024;
    int mmGrid = (N + 63) / 64;
    int aggGrid = (N + 15) / 16;      // 4 nodes/wave, 4 waves/block (R14)
    int nrmGrid = (N + 1023) / 1024;

    // Phase 1: bucket edges + W1/W2/W3 bf16-transpose prepack (3 tail blocks)
    k_bin<<<binGrid + 3, 256, 0, stream>>>(src, dst, E, binD, binS, cntD, cntS, NB, binGrid,
                                           W1, W2, W3, wT1g, wT2g, wT3g);
    // Phase 2: CSR-from-buckets (CSPLIT-way) + out-degree histogram + layer-1 MFMA GEMM
    k_mega<<<2 * NB * CSPLIT + mmGrid, 256, 0, stream>>>(binD, binS, cntD, cntS, in_cnt,
                                                         out_cnt, csr_pad, node_feats,
                                                         wT1g, xwb, N, NB);
    // nsv = rsqrt(out_deg+1) once (replaces per-source cvt+rsq in k_agg1)
    k_nrm<<<nrmGrid, 256, 0, stream>>>(out_cnt, nsv, N);
    // layer-1 aggregation (applies nsrc per source inline): xwb -> h1 (hb)
    k_agg1<<<aggGrid, 256, 0, stream>>>((const uint4*)xwb, in_cnt, csr_pad, nsv, b1,
                                        (uint4*)hb, N);
    // layer 2
    k_xw_mfma<<<mmGrid, 256, 0, stream>>>(hb, out_cnt, wT2g, xwb, N);
    k_agg<<<aggGrid, 256, 0, stream>>>((const uint4*)xwb, in_cnt, csr_pad, b2,
                                       (uint4*)hb, N);
    // layer 3 (+ fused sigmoid gate)
    k_xw_mfma<<<mmGrid, 256, 0, stream>>>(hb, out_cnt, wT3g, xwb, N);
    k_agg_gate<<<aggGrid, 256, 0, stream>>>((const uint4*)xwb, in_cnt, csr_pad, b3,
                                            (uint4*)hb, Wp, bp, wg, N);
    // pooling
    k_pool<<<G * 16, 64, 0, stream>>>(hb, wg, gids, out, N);
}